// Round 4
// baseline (1754.723 us; speedup 1.0000x reference)
//
#include <hip/hip_runtime.h>
#include <hip/hip_bf16.h>
#include <math.h>

// ---------------- problem constants ----------------
#define MROWS 100352      // B*L
#define MHALF 50176
#define DIM   512
#define LL    3136
#define HH    56
#define SSH   3
#define SCALE_QK 0.17677669529663687f

typedef __bf16 bf16;
typedef __bf16 bf16x8 __attribute__((ext_vector_type(8)));
typedef float  f32x4  __attribute__((ext_vector_type(4)));

typedef __attribute__((address_space(1))) void* gas_ptr;
typedef __attribute__((address_space(3))) void* las_ptr;

__device__ __forceinline__ void gload_lds16(const void* g, void* l) {
  __builtin_amdgcn_global_load_lds((gas_ptr)g, (las_ptr)l, 16, 0, 0);
}

// window-ordered row r -> natural row index (applies +SS roll, window reverse)
__device__ __forceinline__ int nat_row(int r) {
  int bw = r / 49;
  int n  = r - bw * 49;
  int b  = bw >> 6;
  int wh = (bw >> 3) & 7;
  int ww = bw & 7;
  int i  = n / 7;
  int j  = n - i * 7;
  int hs = wh * 7 + i + SSH; if (hs >= HH) hs -= HH;
  int ws = ww * 7 + j + SSH; if (ws >= HH) ws -= HH;
  return b * LL + hs * HH + ws;
}

// ---------------- weight transpose + cast: dst[n][k] = (bf16)src[k][n] ----------------
__global__ __launch_bounds__(256) void tcast_kernel(const float* __restrict__ src,
                                                    bf16* __restrict__ dst,
                                                    int Kd, int Nd) {
  __shared__ float t[32][33];
  int tx = threadIdx.x & 31, ty = threadIdx.x >> 5;
  int n0 = blockIdx.x * 32, k0 = blockIdx.y * 32;
  #pragma unroll
  for (int yy = ty; yy < 32; yy += 8)
    t[yy][tx] = src[(size_t)(k0 + yy) * Nd + n0 + tx];
  __syncthreads();
  #pragma unroll
  for (int yy = ty; yy < 32; yy += 8)
    dst[(size_t)(n0 + yy) * Kd + k0 + tx] = (bf16)t[tx][yy];
}

// ---------------- fused rel-pos bias + shift mask table ----------------
// biasM[cls(4)][head(16)][q(49)][k(49)] fp32; cls = (wh==7)<<1 | (ww==7)
__global__ __launch_bounds__(256) void biasM_kernel(const float* __restrict__ table,
                                                    float* __restrict__ biasM) {
  int e = blockIdx.x * 256 + threadIdx.x;
  if (e >= 4 * 16 * 2401) return;
  int k  = e % 49;
  int t  = e / 49;
  int qv = t % 49; t /= 49;
  int head = t & 15;
  int cls  = t >> 4;
  int i1 = qv / 7, j1 = qv - i1 * 7;
  int i2 = k / 7,  j2 = k - i2 * 7;
  float b = table[((i1 - i2 + 6) * 13 + (j1 - j2 + 6)) * 16 + head];
  int labq = ((cls & 2) ? ((i1 < 4) ? 1 : 2) : 0) * 3 + ((cls & 1) ? ((j1 < 4) ? 1 : 2) : 0);
  int labk = ((cls & 2) ? ((i2 < 4) ? 1 : 2) : 0) * 3 + ((cls & 1) ? ((j2 < 4) ? 1 : 2) : 0);
  biasM[e] = b + ((labq == labk) ? 0.f : -100.f);
}

// ---------------- LayerNorm (one wave per row), optional window-gather ----------------
template<int PERM>
__global__ __launch_bounds__(256) void ln_kernel(const float* __restrict__ x,
                                                 const float* __restrict__ gw,
                                                 const float* __restrict__ bw_,
                                                 bf16* __restrict__ out) {
  int wave = threadIdx.x >> 6, lane = threadIdx.x & 63;
  int r = blockIdx.x * 4 + wave;
  int src = PERM ? nat_row(r) : r;
  const float* px = x + (size_t)src * DIM + lane * 8;
  float4 v0 = *(const float4*)px;
  float4 v1 = *(const float4*)(px + 4);
  float s = v0.x + v0.y + v0.z + v0.w + v1.x + v1.y + v1.z + v1.w;
  float q = v0.x*v0.x + v0.y*v0.y + v0.z*v0.z + v0.w*v0.w
          + v1.x*v1.x + v1.y*v1.y + v1.z*v1.z + v1.w*v1.w;
  #pragma unroll
  for (int m = 1; m < 64; m <<= 1) { s += __shfl_xor(s, m); q += __shfl_xor(q, m); }
  float mean = s * (1.f / DIM);
  float var  = q * (1.f / DIM) - mean * mean;
  float rstd = rsqrtf(var + 1e-5f);
  int c0 = lane * 8;
  float4 g0 = *(const float4*)(gw + c0),  g1 = *(const float4*)(gw + c0 + 4);
  float4 b0 = *(const float4*)(bw_ + c0), b1 = *(const float4*)(bw_ + c0 + 4);
  bf16x8 o;
  o[0] = (bf16)((v0.x - mean) * rstd * g0.x + b0.x);
  o[1] = (bf16)((v0.y - mean) * rstd * g0.y + b0.y);
  o[2] = (bf16)((v0.z - mean) * rstd * g0.z + b0.z);
  o[3] = (bf16)((v0.w - mean) * rstd * g0.w + b0.w);
  o[4] = (bf16)((v1.x - mean) * rstd * g1.x + b1.x);
  o[5] = (bf16)((v1.y - mean) * rstd * g1.y + b1.y);
  o[6] = (bf16)((v1.z - mean) * rstd * g1.z + b1.z);
  o[7] = (bf16)((v1.w - mean) * rstd * g1.w + b1.w);
  *(bf16x8*)(out + (size_t)r * DIM + c0) = o;
}

// ================= 256x256 8-phase GEMM (T1+T2+T3+T4+T5) =================
// MODE 1: outF[nat(row)] = resid[nat(row)] + acc + bias   (fp32)   (proj)
// MODE 2: outB = bf16(gelu_exact(acc + bias))                      (fc1)
// MODE 3: outF[row] = resid[row] + acc + bias             (fp32)   (fc2)
// MODE 4: qkv split: Q->outB[wid][n][d], K->outK[wid][n][d], V->outV[wid][d][kv64]

#define MF(a,b,c) __builtin_amdgcn_mfma_f32_16x16x32_bf16((a),(b),(c),0,0,0)
#define BAR() __builtin_amdgcn_s_barrier()
#define WLG() asm volatile("s_waitcnt lgkmcnt(0)" ::: "memory")
#define WVM(n) asm volatile("s_waitcnt vmcnt(" #n ")" ::: "memory")

template<int MODE, int KD, int ND>
__global__ __launch_bounds__(512, 2) void gemm256_kernel(const bf16* __restrict__ A,
                                                         const bf16* __restrict__ Bt,
                                                         const float* __restrict__ bias,
                                                         const float* __restrict__ resid,
                                                         bf16* __restrict__ outB,
                                                         float* __restrict__ outF,
                                                         bf16* __restrict__ outK,
                                                         bf16* __restrict__ outV) {
  constexpr int NTN = ND / 256;
  constexpr int NI  = KD / 128;      // iterations; 2 K-tiles (of 64) each
  __shared__ bf16 lds[65536];        // 128 KiB

  const int tid = threadIdx.x, lane = tid & 63, wv = tid >> 6;
  const int lr = lane & 15, lg = lane >> 4;
  const int wm = wv >> 2, wn = wv & 3;     // 2 x 4 wave grid

  // bijective XCD swizzle (m204)
  int nwg = gridDim.x, orig = blockIdx.x;
  int q = nwg >> 3, r = nwg & 7, xcd = orig & 7;
  int wgid = (xcd < r ? xcd * (q + 1) : r * (q + 1) + (xcd - r) * q) + (orig >> 3);
  int tm = wgid / NTN, tn = wgid % NTN;

  const bf16* gA = A  + (size_t)tm * 256 * KD;
  const bf16* gB = Bt + (size_t)tn * 256 * KD;

  // ds_read bases (elems), swizzled
  const int klg  = (lg * 8) ^ ((lr & 8) ? 16 : 0);
  const int a_rd = (wm * 128 + lr) * 32 + klg;
  const int b_rd = (wn * 64 + lr) * 32 + klg;

  // staging constants
  const int kbOffE = (wv >> 2) * 8192;
  const int kGlob  = (wv >> 2) * 32 + (((lane & 3) * 8) ^ ((lane & 32) ? 16 : 0));
  const int rl0    = ((wv * 2) & 7) * 16 + (lane >> 2);
  const int rl1    = rl0 + 16;
  const int c0off  = ((wv * 2) & 7) * 512;

#define STG(GP, DB, h, koff) \
  gload_lds16((GP) + (size_t)((h) * 128 + rl0) * KD + (koff) + kGlob, \
              (void*)(lds + (DB) + kbOffE + (h) * 4096 + c0off)); \
  gload_lds16((GP) + (size_t)((h) * 128 + rl1) * KD + (koff) + kGlob, \
              (void*)(lds + (DB) + kbOffE + (h) * 4096 + c0off + 512));

  f32x4 acc[8][4];
  #pragma unroll
  for (int i = 0; i < 8; i++)
    #pragma unroll
    for (int j = 0; j < 4; j++) { acc[i][j][0]=0.f; acc[i][j][1]=0.f; acc[i][j][2]=0.f; acc[i][j][3]=0.f; }

  bf16x8 Af[4][2], Bf0[2][2], Bf1[2][2];

  // prologue: tile0 -> b0, tile1 -> b1
  STG(gA, 0,     0, 0)  STG(gA, 0,     1, 0)
  STG(gB, 16384, 0, 0)  STG(gB, 16384, 1, 0)
  STG(gA, 32768, 0, 64) STG(gA, 32768, 1, 64)
  STG(gB, 49152, 0, 64) STG(gB, 49152, 1, 64)
  WVM(8); BAR();

#define PHASES(AB, BB, DOST, KST, ENDW) { \
    _Pragma("unroll") for (int m = 0; m < 4; m++) { \
      Af[m][0] = *(const bf16x8*)(lds + (AB) + m * 512 + a_rd); \
      Af[m][1] = *(const bf16x8*)(lds + (AB) + 8192 + m * 512 + a_rd); } \
    _Pragma("unroll") for (int n = 0; n < 2; n++) { \
      Bf0[n][0] = *(const bf16x8*)(lds + (BB) + n * 512 + b_rd); \
      Bf0[n][1] = *(const bf16x8*)(lds + (BB) + 8192 + n * 512 + b_rd); } \
    BAR(); WLG(); __builtin_amdgcn_s_setprio(1); \
    _Pragma("unroll") for (int m = 0; m < 4; m++) \
      _Pragma("unroll") for (int n = 0; n < 2; n++) { \
        acc[m][n] = MF(Af[m][0], Bf0[n][0], acc[m][n]); \
        acc[m][n] = MF(Af[m][1], Bf0[n][1], acc[m][n]); } \
    __builtin_amdgcn_s_setprio(0); BAR(); \
    _Pragma("unroll") for (int n = 0; n < 2; n++) { \
      Bf1[n][0] = *(const bf16x8*)(lds + (BB) + (n + 2) * 512 + b_rd); \
      Bf1[n][1] = *(const bf16x8*)(lds + (BB) + 8192 + (n + 2) * 512 + b_rd); } \
    if (DOST) { STG(gB, (BB), 0, (KST)) } \
    BAR(); WLG(); __builtin_amdgcn_s_setprio(1); \
    _Pragma("unroll") for (int m = 0; m < 4; m++) \
      _Pragma("unroll") for (int n = 0; n < 2; n++) { \
        acc[m][n + 2] = MF(Af[m][0], Bf1[n][0], acc[m][n + 2]); \
        acc[m][n + 2] = MF(Af[m][1], Bf1[n][1], acc[m][n + 2]); } \
    __builtin_amdgcn_s_setprio(0); BAR(); \
    _Pragma("unroll") for (int m = 0; m < 4; m++) { \
      Af[m][0] = *(const bf16x8*)(lds + (AB) + (m + 4) * 512 + a_rd); \
      Af[m][1] = *(const bf16x8*)(lds + (AB) + 8192 + (m + 4) * 512 + a_rd); } \
    if (DOST) { STG(gB, (BB), 1, (KST)) STG(gA, (AB), 0, (KST)) } \
    BAR(); WLG(); __builtin_amdgcn_s_setprio(1); \
    _Pragma("unroll") for (int m = 0; m < 4; m++) \
      _Pragma("unroll") for (int n = 0; n < 2; n++) { \
        acc[m + 4][n + 2] = MF(Af[m][0], Bf1[n][0], acc[m + 4][n + 2]); \
        acc[m + 4][n + 2] = MF(Af[m][1], Bf1[n][1], acc[m + 4][n + 2]); } \
    __builtin_amdgcn_s_setprio(0); BAR(); \
    if (DOST) { STG(gA, (AB), 1, (KST)) } \
    BAR(); WLG(); __builtin_amdgcn_s_setprio(1); \
    _Pragma("unroll") for (int m = 0; m < 4; m++) \
      _Pragma("unroll") for (int n = 0; n < 2; n++) { \
        acc[m + 4][n] = MF(Af[m][0], Bf0[n][0], acc[m + 4][n]); \
        acc[m + 4][n] = MF(Af[m][1], Bf0[n][1], acc[m + 4][n]); } \
    __builtin_amdgcn_s_setprio(0); ENDW; BAR(); \
  }

  #pragma unroll 1
  for (int I = 0; I < NI - 1; ++I) {
    int ke = (2 * I + 2) * 64;
    PHASES(0,     16384, 1, ke,      WVM(6));
    PHASES(32768, 49152, 1, ke + 64, WVM(6));
  }
  PHASES(0,     16384, 0, 0, WVM(0));
  PHASES(32768, 49152, 0, 0, ((void)0));

#undef PHASES
#undef STG

  // epilogue
  #pragma unroll
  for (int fm = 0; fm < 8; fm++) {
    #pragma unroll
    for (int rr = 0; rr < 4; rr++) {
      int row = tm * 256 + wm * 128 + fm * 16 + lg * 4 + rr;
      int orow = (MODE == 1) ? nat_row(row) : row;
      int win = 0, nn = 0;
      if (MODE == 4) { win = row / 49; nn = row - win * 49; }
      #pragma unroll
      for (int fn = 0; fn < 4; fn++) {
        int col = tn * 256 + wn * 64 + fn * 16 + lr;
        float v = acc[fm][fn][rr] + bias[col];
        if (MODE == 1) {
          outF[(size_t)orow * ND + col] = resid[(size_t)orow * ND + col] + v;
        } else if (MODE == 2) {
          float g = 0.5f * v * (1.f + erff(v * 0.70710678118654752f));
          outB[(size_t)row * ND + col] = (bf16)g;
        } else if (MODE == 3) {
          outF[(size_t)row * ND + col] = resid[(size_t)row * ND + col] + v;
        } else if (MODE == 4) {
          int c = col & 511;
          int head = c >> 5, d = c & 31;
          size_t sb = (size_t)(win * 16 + head);
          if (col < 512)        outB[sb * 1568 + nn * 32 + d] = (bf16)v;
          else if (col < 1024)  outK[sb * 1568 + nn * 32 + d] = (bf16)v;
          else                  outV[sb * 2048 + d * 64 + nn] = (bf16)v;
        }
      }
    }
  }
}

// ---------------- windowed attention: one wave per (window, head) ----------------
__global__ __launch_bounds__(256) void attn_kernel(const bf16* __restrict__ Qb,
                                                   const bf16* __restrict__ Kb,
                                                   const bf16* __restrict__ Vt,
                                                   const float* __restrict__ biasM,
                                                   bf16* __restrict__ attnO) {
  __shared__ bf16 P[4][64 * 72];   // per-wave P tile, row stride 72 elems
  int wave = threadIdx.x >> 6, lane = threadIdx.x & 63;
  int lr = lane & 15, lg = lane >> 4;
  int wid = blockIdx.x * 4 + wave;      // win*16 + head
  int win = wid >> 4, head = wid & 15;
  int wh = (win >> 3) & 7, ww = win & 7;
  int cls = ((wh == 7) ? 2 : 0) | ((ww == 7) ? 1 : 0);
  const bf16* qp = Qb + (size_t)wid * 1568;
  const bf16* kp = Kb + (size_t)wid * 1568;
  const bf16* vp = Vt + (size_t)wid * 2048;
  const float* bp = biasM + (size_t)cls * 38416 + head * 2401;

  f32x4 zero4 = {0.f, 0.f, 0.f, 0.f};
  bf16x8 aq[4], bk[4];
  #pragma unroll
  for (int mi = 0; mi < 4; mi++) {
    int qq = mi * 16 + lr; if (qq > 48) qq = 48;
    aq[mi] = *(const bf16x8*)(qp + qq * 32 + lg * 8);
    bk[mi] = *(const bf16x8*)(kp + qq * 32 + lg * 8);
  }
  f32x4 sacc[4][4];
  #pragma unroll
  for (int mi = 0; mi < 4; mi++)
    #pragma unroll
    for (int ni = 0; ni < 4; ni++)
      sacc[mi][ni] = __builtin_amdgcn_mfma_f32_16x16x32_bf16(aq[mi], bk[ni], zero4, 0, 0, 0);

  float rsum[4][4];
  #pragma unroll
  for (int mi = 0; mi < 4; mi++) {
    #pragma unroll
    for (int rr = 0; rr < 4; rr++) {
      int qrow = mi * 16 + lg * 4 + rr;
      int qc = qrow > 48 ? 48 : qrow;
      const float* bq = bp + qc * 49;
      float pv[4];
      float mv = -3.0e30f;
      #pragma unroll
      for (int ni = 0; ni < 4; ni++) {
        int key = ni * 16 + lr;
        float v = (key < 49) ? sacc[mi][ni][rr] * SCALE_QK + bq[key] : -1e30f;
        pv[ni] = v;
        mv = fmaxf(mv, v);
      }
      #pragma unroll
      for (int m = 1; m < 16; m <<= 1) mv = fmaxf(mv, __shfl_xor(mv, m));
      float sum = 0.f;
      #pragma unroll
      for (int ni = 0; ni < 4; ni++) {
        float p = __expf(pv[ni] - mv);
        sum += p;
        P[wave][qrow * 72 + ni * 16 + lr] = (bf16)p;
      }
      #pragma unroll
      for (int m = 1; m < 16; m <<= 1) sum += __shfl_xor(sum, m);
      rsum[mi][rr] = sum;
    }
  }
  __syncthreads();

  f32x4 oacc[4][2];
  #pragma unroll
  for (int mi = 0; mi < 4; mi++) { oacc[mi][0] = zero4; oacc[mi][1] = zero4; }
  #pragma unroll
  for (int ks = 0; ks < 2; ks++) {
    bf16x8 bv[2];
    #pragma unroll
    for (int n2 = 0; n2 < 2; n2++)
      bv[n2] = *(const bf16x8*)(vp + (n2 * 16 + lr) * 64 + ks * 32 + lg * 8);
    #pragma unroll
    for (int mi = 0; mi < 4; mi++) {
      bf16x8 ap = *(const bf16x8*)(&P[wave][(mi * 16 + lr) * 72 + ks * 32 + lg * 8]);
      #pragma unroll
      for (int n2 = 0; n2 < 2; n2++)
        oacc[mi][n2] = __builtin_amdgcn_mfma_f32_16x16x32_bf16(ap, bv[n2], oacc[mi][n2], 0, 0, 0);
    }
  }
  #pragma unroll
  for (int mi = 0; mi < 4; mi++) {
    #pragma unroll
    for (int rr = 0; rr < 4; rr++) {
      int qrow = mi * 16 + lg * 4 + rr;
      if (qrow < 49) {
        float inv = 1.f / rsum[mi][rr];
        #pragma unroll
        for (int n2 = 0; n2 < 2; n2++)
          attnO[((size_t)win * 49 + qrow) * DIM + head * 32 + n2 * 16 + lr] =
              (bf16)(oacc[mi][n2][rr] * inv);
      }
    }
  }
}

// ---------------- launch ----------------
extern "C" void kernel_launch(void* const* d_in, const int* in_sizes, int n_in,
                              void* d_out, int out_size, void* d_ws, size_t ws_size,
                              hipStream_t stream) {
  const float* x      = (const float*)d_in[0];
  const float* n1g    = (const float*)d_in[1];
  const float* n1b    = (const float*)d_in[2];
  const float* qkv_w  = (const float*)d_in[3];
  const float* qkv_b  = (const float*)d_in[4];
  const float* tabl   = (const float*)d_in[5];
  const float* proj_w = (const float*)d_in[6];
  const float* proj_b = (const float*)d_in[7];
  const float* n2g    = (const float*)d_in[8];
  const float* n2b    = (const float*)d_in[9];
  const float* fc1_w  = (const float*)d_in[10];
  const float* fc1_b  = (const float*)d_in[11];
  const float* fc2_w  = (const float*)d_in[12];
  const float* fc2_b  = (const float*)d_in[13];
  float* out = (float*)d_out;

  char* ws = (char*)d_ws;
  // region 0: RegA (X1n -> attnO -> X2n)            102,760,448 B
  // region 1: Qb + Kb (later h1 chunks)             308,281,344 B
  // region 2: Vt(134,217,728) + biasM -> later x2   205,520,896 B
  // region 3: bf16 weights                            6,291,456 B
  bf16*  RegA   = (bf16*)ws;
  bf16*  Qb     = (bf16*)(ws + 102760448);
  bf16*  Kb     = (bf16*)(ws + 102760448 + 102760448);
  bf16*  RegB   = Qb;  // h1 chunks reuse Qb/Kb space
  char*  reg2   = ws + 411041792;
  bf16*  Vt     = (bf16*)reg2;
  float* biasM  = (float*)(reg2 + 134217728);
  float* x2     = (float*)reg2;
  bf16*  qkvWt  = (bf16*)(ws + 616562688);
  bf16*  projWt = qkvWt + 1536 * 512;
  bf16*  fc1Wt  = projWt + 512 * 512;
  bf16*  fc2Wt  = fc1Wt + 2048 * 512;

  // bias+mask table (615 KB) and weights -> bf16 (N,K)
  biasM_kernel<<<(4 * 16 * 2401 + 255) / 256, 256, 0, stream>>>(tabl, biasM);
  tcast_kernel<<<dim3(1536 / 32, 512 / 32), 256, 0, stream>>>(qkv_w, qkvWt, 512, 1536);
  tcast_kernel<<<dim3(512 / 32, 512 / 32), 256, 0, stream>>>(proj_w, projWt, 512, 512);
  tcast_kernel<<<dim3(2048 / 32, 512 / 32), 256, 0, stream>>>(fc1_w, fc1Wt, 512, 2048);
  tcast_kernel<<<dim3(512 / 32, 2048 / 32), 256, 0, stream>>>(fc2_w, fc2Wt, 2048, 512);

  // LN1 + shift + window partition (window-ordered bf16 rows)
  ln_kernel<1><<<MROWS / 4, 256, 0, stream>>>(x, n1g, n1b, RegA);
  // qkv GEMM with Q/K head-major + V transposed split epilogue
  gemm256_kernel<4, 512, 1536><<<(MROWS / 256) * 6, 512, 0, stream>>>(
      RegA, qkvWt, qkv_b, nullptr, Qb, nullptr, Kb, Vt);
  // attention (2048 windows * 16 heads, 4 waves/block)
  attn_kernel<<<2048 * 16 / 4, 256, 0, stream>>>(Qb, Kb, Vt, biasM, RegA);
  // proj + residual + window-reverse scatter -> x2 (fp32, natural order)
  gemm256_kernel<1, 512, 512><<<(MROWS / 256) * 2, 512, 0, stream>>>(
      RegA, projWt, proj_b, x, nullptr, x2, nullptr, nullptr);
  // LN2
  ln_kernel<0><<<MROWS / 4, 256, 0, stream>>>(x2, n2g, n2b, RegA);
  // MLP in two row-chunks (h1 chunk reuses RegB = Qb/Kb space)
  for (int c = 0; c < 2; ++c) {
    const bf16* a1 = RegA + (size_t)c * MHALF * 512;
    gemm256_kernel<2, 512, 2048><<<(MHALF / 256) * 8, 512, 0, stream>>>(
        a1, fc1Wt, fc1_b, nullptr, RegB, nullptr, nullptr, nullptr);
    gemm256_kernel<3, 2048, 512><<<(MHALF / 256) * 2, 512, 0, stream>>>(
        RegB, fc2Wt, fc2_b, x2 + (size_t)c * MHALF * 512, nullptr,
        out + (size_t)c * MHALF * 512, nullptr, nullptr);
  }
}

// Round 6
// 1743.924 us; speedup vs baseline: 1.0062x; 1.0062x over previous
//
#include <hip/hip_runtime.h>
#include <hip/hip_bf16.h>
#include <math.h>

// ---------------- problem constants ----------------
#define MROWS 100352      // B*L
#define MHALF 50176
#define DIM   512
#define LL    3136
#define HH    56
#define SSH   3
#define SCALE_QK 0.17677669529663687f

typedef __bf16 bf16;
typedef __bf16 bf16x8 __attribute__((ext_vector_type(8)));
typedef __bf16 bf16x4 __attribute__((ext_vector_type(4)));
typedef float  f32x4  __attribute__((ext_vector_type(4)));

typedef __attribute__((address_space(1))) void* gas_ptr;
typedef __attribute__((address_space(3))) void* las_ptr;

__device__ __forceinline__ void gload_lds16(const void* g, void* l) {
  __builtin_amdgcn_global_load_lds((gas_ptr)g, (las_ptr)l, 16, 0, 0);
}

// window-ordered row r -> natural row index (applies +SS roll, window reverse)
__device__ __forceinline__ int nat_row(int r) {
  int bw = r / 49;
  int n  = r - bw * 49;
  int b  = bw >> 6;
  int wh = (bw >> 3) & 7;
  int ww = bw & 7;
  int i  = n / 7;
  int j  = n - i * 7;
  int hs = wh * 7 + i + SSH; if (hs >= HH) hs -= HH;
  int ws = ww * 7 + j + SSH; if (ws >= HH) ws -= HH;
  return b * LL + hs * HH + ws;
}

// ---------------- weight transpose + cast: dst[n][k] = (bf16)src[k][n] ----------------
__global__ __launch_bounds__(256) void tcast_kernel(const float* __restrict__ src,
                                                    bf16* __restrict__ dst,
                                                    int Kd, int Nd) {
  __shared__ float t[32][33];
  int tx = threadIdx.x & 31, ty = threadIdx.x >> 5;
  int n0 = blockIdx.x * 32, k0 = blockIdx.y * 32;
  #pragma unroll
  for (int yy = ty; yy < 32; yy += 8)
    t[yy][tx] = src[(size_t)(k0 + yy) * Nd + n0 + tx];
  __syncthreads();
  #pragma unroll
  for (int yy = ty; yy < 32; yy += 8)
    dst[(size_t)(n0 + yy) * Kd + k0 + tx] = (bf16)t[tx][yy];
}

// ---------------- fused rel-pos bias + shift mask table ----------------
// biasM[cls(4)][head(16)][q(49)][k(49)] fp32; cls = (wh==7)<<1 | (ww==7)
__global__ __launch_bounds__(256) void biasM_kernel(const float* __restrict__ table,
                                                    float* __restrict__ biasM) {
  int e = blockIdx.x * 256 + threadIdx.x;
  if (e >= 4 * 16 * 2401) return;
  int k  = e % 49;
  int t  = e / 49;
  int qv = t % 49; t /= 49;
  int head = t & 15;
  int cls  = t >> 4;
  int i1 = qv / 7, j1 = qv - i1 * 7;
  int i2 = k / 7,  j2 = k - i2 * 7;
  float b = table[((i1 - i2 + 6) * 13 + (j1 - j2 + 6)) * 16 + head];
  int labq = ((cls & 2) ? ((i1 < 4) ? 1 : 2) : 0) * 3 + ((cls & 1) ? ((j1 < 4) ? 1 : 2) : 0);
  int labk = ((cls & 2) ? ((i2 < 4) ? 1 : 2) : 0) * 3 + ((cls & 1) ? ((j2 < 4) ? 1 : 2) : 0);
  biasM[e] = b + ((labq == labk) ? 0.f : -100.f);
}

// ---------------- LayerNorm (one wave per row), optional window-gather ----------------
template<int PERM>
__global__ __launch_bounds__(256) void ln_kernel(const float* __restrict__ x,
                                                 const float* __restrict__ gw,
                                                 const float* __restrict__ bw_,
                                                 bf16* __restrict__ out) {
  int wave = threadIdx.x >> 6, lane = threadIdx.x & 63;
  int r = blockIdx.x * 4 + wave;
  int src = PERM ? nat_row(r) : r;
  const float* px = x + (size_t)src * DIM + lane * 8;
  float4 v0 = *(const float4*)px;
  float4 v1 = *(const float4*)(px + 4);
  float s = v0.x + v0.y + v0.z + v0.w + v1.x + v1.y + v1.z + v1.w;
  float q = v0.x*v0.x + v0.y*v0.y + v0.z*v0.z + v0.w*v0.w
          + v1.x*v1.x + v1.y*v1.y + v1.z*v1.z + v1.w*v1.w;
  #pragma unroll
  for (int m = 1; m < 64; m <<= 1) { s += __shfl_xor(s, m); q += __shfl_xor(q, m); }
  float mean = s * (1.f / DIM);
  float var  = q * (1.f / DIM) - mean * mean;
  float rstd = rsqrtf(var + 1e-5f);
  int c0 = lane * 8;
  float4 g0 = *(const float4*)(gw + c0),  g1 = *(const float4*)(gw + c0 + 4);
  float4 b0 = *(const float4*)(bw_ + c0), b1 = *(const float4*)(bw_ + c0 + 4);
  bf16x8 o;
  o[0] = (bf16)((v0.x - mean) * rstd * g0.x + b0.x);
  o[1] = (bf16)((v0.y - mean) * rstd * g0.y + b0.y);
  o[2] = (bf16)((v0.z - mean) * rstd * g0.z + b0.z);
  o[3] = (bf16)((v0.w - mean) * rstd * g0.w + b0.w);
  o[4] = (bf16)((v1.x - mean) * rstd * g1.x + b1.x);
  o[5] = (bf16)((v1.y - mean) * rstd * g1.y + b1.y);
  o[6] = (bf16)((v1.z - mean) * rstd * g1.z + b1.z);
  o[7] = (bf16)((v1.w - mean) * rstd * g1.w + b1.w);
  *(bf16x8*)(out + (size_t)r * DIM + c0) = o;
}

// ================= 256x256 8-phase GEMM (T1+T2+T3+T4+T5) =================
// MODE 1: outF[nat(row)] = resid[nat(row)] + acc + bias   (fp32)   (proj)
// MODE 2: outB = bf16(gelu_exact(acc + bias))                      (fc1)
// MODE 3: outF[row] = resid[row] + acc + bias             (fp32)   (fc2)
// MODE 4: qkv split head-major: Q/K/V -> out*[wid][nn][32]

#define MF(a,b,c) __builtin_amdgcn_mfma_f32_16x16x32_bf16((a),(b),(c),0,0,0)
#define BAR() __builtin_amdgcn_s_barrier()
#define WLG() asm volatile("s_waitcnt lgkmcnt(0)" ::: "memory")
#define WVM(n) asm volatile("s_waitcnt vmcnt(" #n ")" ::: "memory")

template<int MODE, int KD, int ND>
__global__ __launch_bounds__(512, 2) void gemm256_kernel(const bf16* __restrict__ A,
                                                         const bf16* __restrict__ Bt,
                                                         const float* __restrict__ bias,
                                                         const float* __restrict__ resid,
                                                         bf16* __restrict__ outB,
                                                         float* __restrict__ outF,
                                                         bf16* __restrict__ outK,
                                                         bf16* __restrict__ outV) {
  constexpr int NTN = ND / 256;
  constexpr int NI  = KD / 128;      // iterations; 2 K-tiles (of 64) each
  __shared__ bf16 lds[65536];        // 128 KiB

  const int tid = threadIdx.x, lane = tid & 63, wv = tid >> 6;
  const int lr = lane & 15, lg = lane >> 4;
  const int wm = wv >> 2, wn = wv & 3;     // 2 x 4 wave grid

  // bijective XCD swizzle (m204)
  int nwg = gridDim.x, orig = blockIdx.x;
  int q = nwg >> 3, r = nwg & 7, xcd = orig & 7;
  int wgid = (xcd < r ? xcd * (q + 1) : r * (q + 1) + (xcd - r) * q) + (orig >> 3);
  int tm = wgid / NTN, tn = wgid % NTN;

  const bf16* gA = A  + (size_t)tm * 256 * KD;
  const bf16* gB = Bt + (size_t)tn * 256 * KD;

  // ds_read bases (elems), swizzled
  const int klg  = (lg * 8) ^ ((lr & 8) ? 16 : 0);
  const int a_rd = (wm * 128 + lr) * 32 + klg;
  const int b_rd = (wn * 64 + lr) * 32 + klg;

  // staging constants
  const int kbOffE = (wv >> 2) * 8192;
  const int kGlob  = (wv >> 2) * 32 + (((lane & 3) * 8) ^ ((lane & 32) ? 16 : 0));
  const int rl0    = ((wv * 2) & 7) * 16 + (lane >> 2);
  const int rl1    = rl0 + 16;
  const int c0off  = ((wv * 2) & 7) * 512;

#define STG(GP, DB, h, koff) \
  gload_lds16((GP) + (size_t)((h) * 128 + rl0) * KD + (koff) + kGlob, \
              (void*)(lds + (DB) + kbOffE + (h) * 4096 + c0off)); \
  gload_lds16((GP) + (size_t)((h) * 128 + rl1) * KD + (koff) + kGlob, \
              (void*)(lds + (DB) + kbOffE + (h) * 4096 + c0off + 512));

  f32x4 acc[8][4];
  #pragma unroll
  for (int i = 0; i < 8; i++)
    #pragma unroll
    for (int j = 0; j < 4; j++) { acc[i][j][0]=0.f; acc[i][j][1]=0.f; acc[i][j][2]=0.f; acc[i][j][3]=0.f; }

  bf16x8 Af[4][2], Bf0[2][2], Bf1[2][2];

  // prologue: tile0 -> b0, tile1 -> b1
  STG(gA, 0,     0, 0)  STG(gA, 0,     1, 0)
  STG(gB, 16384, 0, 0)  STG(gB, 16384, 1, 0)
  STG(gA, 32768, 0, 64) STG(gA, 32768, 1, 64)
  STG(gB, 49152, 0, 64) STG(gB, 49152, 1, 64)
  WVM(8); BAR();

#define PHASES(AB, BB, DOST, KST, ENDW) { \
    _Pragma("unroll") for (int m = 0; m < 4; m++) { \
      Af[m][0] = *(const bf16x8*)(lds + (AB) + m * 512 + a_rd); \
      Af[m][1] = *(const bf16x8*)(lds + (AB) + 8192 + m * 512 + a_rd); } \
    _Pragma("unroll") for (int n = 0; n < 2; n++) { \
      Bf0[n][0] = *(const bf16x8*)(lds + (BB) + n * 512 + b_rd); \
      Bf0[n][1] = *(const bf16x8*)(lds + (BB) + 8192 + n * 512 + b_rd); } \
    BAR(); WLG(); __builtin_amdgcn_s_setprio(1); \
    _Pragma("unroll") for (int m = 0; m < 4; m++) \
      _Pragma("unroll") for (int n = 0; n < 2; n++) { \
        acc[m][n] = MF(Af[m][0], Bf0[n][0], acc[m][n]); \
        acc[m][n] = MF(Af[m][1], Bf0[n][1], acc[m][n]); } \
    __builtin_amdgcn_s_setprio(0); BAR(); \
    _Pragma("unroll") for (int n = 0; n < 2; n++) { \
      Bf1[n][0] = *(const bf16x8*)(lds + (BB) + (n + 2) * 512 + b_rd); \
      Bf1[n][1] = *(const bf16x8*)(lds + (BB) + 8192 + (n + 2) * 512 + b_rd); } \
    if (DOST) { STG(gB, (BB), 0, (KST)) } \
    BAR(); WLG(); __builtin_amdgcn_s_setprio(1); \
    _Pragma("unroll") for (int m = 0; m < 4; m++) \
      _Pragma("unroll") for (int n = 0; n < 2; n++) { \
        acc[m][n + 2] = MF(Af[m][0], Bf1[n][0], acc[m][n + 2]); \
        acc[m][n + 2] = MF(Af[m][1], Bf1[n][1], acc[m][n + 2]); } \
    __builtin_amdgcn_s_setprio(0); BAR(); \
    _Pragma("unroll") for (int m = 0; m < 4; m++) { \
      Af[m][0] = *(const bf16x8*)(lds + (AB) + (m + 4) * 512 + a_rd); \
      Af[m][1] = *(const bf16x8*)(lds + (AB) + 8192 + (m + 4) * 512 + a_rd); } \
    if (DOST) { STG(gB, (BB), 1, (KST)) STG(gA, (AB), 0, (KST)) } \
    BAR(); WLG(); __builtin_amdgcn_s_setprio(1); \
    _Pragma("unroll") for (int m = 0; m < 4; m++) \
      _Pragma("unroll") for (int n = 0; n < 2; n++) { \
        acc[m + 4][n + 2] = MF(Af[m][0], Bf1[n][0], acc[m + 4][n + 2]); \
        acc[m + 4][n + 2] = MF(Af[m][1], Bf1[n][1], acc[m + 4][n + 2]); } \
    __builtin_amdgcn_s_setprio(0); BAR(); \
    if (DOST) { STG(gA, (AB), 1, (KST)) } \
    BAR(); WLG(); __builtin_amdgcn_s_setprio(1); \
    _Pragma("unroll") for (int m = 0; m < 4; m++) \
      _Pragma("unroll") for (int n = 0; n < 2; n++) { \
        acc[m + 4][n] = MF(Af[m][0], Bf0[n][0], acc[m + 4][n]); \
        acc[m + 4][n] = MF(Af[m][1], Bf0[n][1], acc[m + 4][n]); } \
    __builtin_amdgcn_s_setprio(0); ENDW; BAR(); \
  }

  #pragma unroll 1
  for (int I = 0; I < NI - 1; ++I) {
    int ke = (2 * I + 2) * 64;
    PHASES(0,     16384, 1, ke,      WVM(6));
    PHASES(32768, 49152, 1, ke + 64, WVM(6));
  }
  PHASES(0,     16384, 0, 0, WVM(0));
  PHASES(32768, 49152, 0, 0, ((void)0));

#undef PHASES
#undef STG

  // epilogue
  #pragma unroll
  for (int fm = 0; fm < 8; fm++) {
    #pragma unroll
    for (int rr = 0; rr < 4; rr++) {
      int row = tm * 256 + wm * 128 + fm * 16 + lg * 4 + rr;
      int orow = (MODE == 1) ? nat_row(row) : row;
      int win = 0, nn = 0;
      if (MODE == 4) { win = row / 49; nn = row - win * 49; }
      #pragma unroll
      for (int fn = 0; fn < 4; fn++) {
        int col = tn * 256 + wn * 64 + fn * 16 + lr;
        float v = acc[fm][fn][rr] + bias[col];
        if (MODE == 1) {
          outF[(size_t)orow * ND + col] = resid[(size_t)orow * ND + col] + v;
        } else if (MODE == 2) {
          float g = 0.5f * v * (1.f + erff(v * 0.70710678118654752f));
          outB[(size_t)row * ND + col] = (bf16)g;
        } else if (MODE == 3) {
          outF[(size_t)row * ND + col] = resid[(size_t)row * ND + col] + v;
        } else if (MODE == 4) {
          int c = col & 511;
          int head = c >> 5, d = c & 31;
          size_t sb = (size_t)(win * 16 + head) * 1568 + nn * 32 + d;
          if (col < 512)        outB[sb] = (bf16)v;
          else if (col < 1024)  outK[sb] = (bf16)v;
          else                  outV[sb] = (bf16)v;
        }
      }
    }
  }
}

// ---------------- windowed attention: one wave per (window, head) ----------------
// Q/K/V head-major [wid][nn][32]; V transposed through per-wave LDS.
__global__ __launch_bounds__(256) void attn_kernel(const bf16* __restrict__ Qb,
                                                   const bf16* __restrict__ Kb,
                                                   const bf16* __restrict__ Vb,
                                                   const float* __restrict__ biasM,
                                                   bf16* __restrict__ attnO) {
  __shared__ bf16 P[4][64 * 72];    // per-wave P tile, row stride 72 elems
  __shared__ bf16 Vs[4][49 * 36];   // per-wave V tile, row stride 36 elems (72 B)
  int wave = threadIdx.x >> 6, lane = threadIdx.x & 63;
  int lr = lane & 15, lg = lane >> 4;
  int wid = blockIdx.x * 4 + wave;      // win*16 + head
  int win = wid >> 4, head = wid & 15;
  int wh = (win >> 3) & 7, ww = win & 7;
  int cls = ((wh == 7) ? 2 : 0) | ((ww == 7) ? 1 : 0);
  const bf16* qp = Qb + (size_t)wid * 1568;
  const bf16* kp = Kb + (size_t)wid * 1568;
  const bf16* vp = Vb + (size_t)wid * 1568;
  const float* bp = biasM + (size_t)cls * 38416 + head * 2401;

  // stage V [49][32] -> Vs rows stride 36 (coalesced 16B global loads)
  for (int i = lane; i < 196; i += 64) {
    bf16x8 v = *(const bf16x8*)(vp + i * 8);
    int nn = i >> 2, d = (i & 3) * 8;
    ((bf16x4*)(&Vs[wave][nn * 36 + d]))[0] = ((bf16x4*)&v)[0];
    ((bf16x4*)(&Vs[wave][nn * 36 + d + 4]))[0] = ((bf16x4*)&v)[1];
  }

  f32x4 zero4 = {0.f, 0.f, 0.f, 0.f};
  bf16x8 aq[4], bk[4];
  #pragma unroll
  for (int mi = 0; mi < 4; mi++) {
    int qq = mi * 16 + lr; if (qq > 48) qq = 48;
    aq[mi] = *(const bf16x8*)(qp + qq * 32 + lg * 8);
    bk[mi] = *(const bf16x8*)(kp + qq * 32 + lg * 8);
  }
  f32x4 sacc[4][4];
  #pragma unroll
  for (int mi = 0; mi < 4; mi++)
    #pragma unroll
    for (int ni = 0; ni < 4; ni++)
      sacc[mi][ni] = __builtin_amdgcn_mfma_f32_16x16x32_bf16(aq[mi], bk[ni], zero4, 0, 0, 0);

  float rsum[4][4];
  #pragma unroll
  for (int mi = 0; mi < 4; mi++) {
    #pragma unroll
    for (int rr = 0; rr < 4; rr++) {
      int qrow = mi * 16 + lg * 4 + rr;
      int qc = qrow > 48 ? 48 : qrow;
      const float* bq = bp + qc * 49;
      float pv[4];
      float mv = -3.0e30f;
      #pragma unroll
      for (int ni = 0; ni < 4; ni++) {
        int key = ni * 16 + lr;
        float v = (key < 49) ? sacc[mi][ni][rr] * SCALE_QK + bq[key] : -1e30f;
        pv[ni] = v;
        mv = fmaxf(mv, v);
      }
      #pragma unroll
      for (int m = 1; m < 16; m <<= 1) mv = fmaxf(mv, __shfl_xor(mv, m));
      float sum = 0.f;
      #pragma unroll
      for (int ni = 0; ni < 4; ni++) {
        float p = __expf(pv[ni] - mv);
        sum += p;
        P[wave][qrow * 72 + ni * 16 + lr] = (bf16)p;
      }
      #pragma unroll
      for (int m = 1; m < 16; m <<= 1) sum += __shfl_xor(sum, m);
      rsum[mi][rr] = sum;
    }
  }
  __syncthreads();

  f32x4 oacc[4][2];
  #pragma unroll
  for (int mi = 0; mi < 4; mi++) { oacc[mi][0] = zero4; oacc[mi][1] = zero4; }
  #pragma unroll
  for (int ks = 0; ks < 2; ks++) {
    bf16x8 bv[2];
    #pragma unroll
    for (int n2 = 0; n2 < 2; n2++)
      #pragma unroll
      for (int j = 0; j < 8; j++) {
        int kv = ks * 32 + lg * 8 + j;
        if (kv > 48) kv = 48;           // P there is exactly 0
        bv[n2][j] = Vs[wave][kv * 36 + n2 * 16 + lr];
      }
    #pragma unroll
    for (int mi = 0; mi < 4; mi++) {
      bf16x8 ap = *(const bf16x8*)(&P[wave][(mi * 16 + lr) * 72 + ks * 32 + lg * 8]);
      #pragma unroll
      for (int n2 = 0; n2 < 2; n2++)
        oacc[mi][n2] = __builtin_amdgcn_mfma_f32_16x16x32_bf16(ap, bv[n2], oacc[mi][n2], 0, 0, 0);
    }
  }
  #pragma unroll
  for (int mi = 0; mi < 4; mi++) {
    #pragma unroll
    for (int rr = 0; rr < 4; rr++) {
      int qrow = mi * 16 + lg * 4 + rr;
      if (qrow < 49) {
        float inv = 1.f / rsum[mi][rr];
        #pragma unroll
        for (int n2 = 0; n2 < 2; n2++)
          attnO[((size_t)win * 49 + qrow) * DIM + head * 32 + n2 * 16 + lr] =
              (bf16)(oacc[mi][n2][rr] * inv);
      }
    }
  }
}

// ---------------- launch ----------------
extern "C" void kernel_launch(void* const* d_in, const int* in_sizes, int n_in,
                              void* d_out, int out_size, void* d_ws, size_t ws_size,
                              hipStream_t stream) {
  const float* x      = (const float*)d_in[0];
  const float* n1g    = (const float*)d_in[1];
  const float* n1b    = (const float*)d_in[2];
  const float* qkv_w  = (const float*)d_in[3];
  const float* qkv_b  = (const float*)d_in[4];
  const float* tabl   = (const float*)d_in[5];
  const float* proj_w = (const float*)d_in[6];
  const float* proj_b = (const float*)d_in[7];
  const float* n2g    = (const float*)d_in[8];
  const float* n2b    = (const float*)d_in[9];
  const float* fc1_w  = (const float*)d_in[10];
  const float* fc1_b  = (const float*)d_in[11];
  const float* fc2_w  = (const float*)d_in[12];
  const float* fc2_b  = (const float*)d_in[13];
  float* out = (float*)d_out;

  char* ws = (char*)d_ws;
  // region 0: RegA (X1n -> attnO -> X2n)                 102,760,448 B
  // region 1: Qb + Kb (later h1 chunks = RegB)           205,520,896 B
  // region 2: Vb(102,760,448) + biasM | later x2 (fp32)  205,520,896 B
  // region 3: bf16 weights                                 6,291,456 B
  bf16*  RegA   = (bf16*)ws;
  bf16*  Qb     = (bf16*)(ws + 102760448);
  bf16*  Kb     = (bf16*)(ws + 102760448 + 102760448);
  bf16*  RegB   = Qb;  // h1 chunks reuse Qb/Kb space
  char*  reg2   = ws + 308281344;
  bf16*  Vb     = (bf16*)reg2;
  float* biasM  = (float*)(reg2 + 102760448);
  float* x2     = (float*)reg2;
  bf16*  qkvWt  = (bf16*)(ws + 308281344 + 205520896);
  bf16*  projWt = qkvWt + 1536 * 512;
  bf16*  fc1Wt  = projWt + 512 * 512;
  bf16*  fc2Wt  = fc1Wt + 2048 * 512;

  // bias+mask table (615 KB) and weights -> bf16 (N,K)
  biasM_kernel<<<(4 * 16 * 2401 + 255) / 256, 256, 0, stream>>>(tabl, biasM);
  tcast_kernel<<<dim3(1536 / 32, 512 / 32), 256, 0, stream>>>(qkv_w, qkvWt, 512, 1536);
  tcast_kernel<<<dim3(512 / 32, 512 / 32), 256, 0, stream>>>(proj_w, projWt, 512, 512);
  tcast_kernel<<<dim3(2048 / 32, 512 / 32), 256, 0, stream>>>(fc1_w, fc1Wt, 512, 2048);
  tcast_kernel<<<dim3(512 / 32, 2048 / 32), 256, 0, stream>>>(fc2_w, fc2Wt, 2048, 512);

  // LN1 + shift + window partition (window-ordered bf16 rows)
  ln_kernel<1><<<MROWS / 4, 256, 0, stream>>>(x, n1g, n1b, RegA);
  // qkv GEMM, head-major split epilogue (all-dense writes)
  gemm256_kernel<4, 512, 1536><<<(MROWS / 256) * 6, 512, 0, stream>>>(
      RegA, qkvWt, qkv_b, nullptr, Qb, nullptr, Kb, Vb);
  // attention (2048 windows * 16 heads, 4 waves/block)
  attn_kernel<<<2048 * 16 / 4, 256, 0, stream>>>(Qb, Kb, Vb, biasM, RegA);
  // proj + residual + window-reverse scatter -> x2 (fp32, natural order)
  gemm256_kernel<1, 512, 512><<<(MROWS / 256) * 2, 512, 0, stream>>>(
      RegA, projWt, proj_b, x, nullptr, x2, nullptr, nullptr);
  // LN2
  ln_kernel<0><<<MROWS / 4, 256, 0, stream>>>(x2, n2g, n2b, RegA);
  // MLP in two row-chunks (h1 chunk reuses RegB = Qb/Kb space)
  for (int c = 0; c < 2; ++c) {
    const bf16* a1 = RegA + (size_t)c * MHALF * 512;
    gemm256_kernel<2, 512, 2048><<<(MHALF / 256) * 8, 512, 0, stream>>>(
        a1, fc1Wt, fc1_b, nullptr, RegB, nullptr, nullptr, nullptr);
    gemm256_kernel<3, 2048, 512><<<(MHALF / 256) * 2, 512, 0, stream>>>(
        RegB, fc2Wt, fc2_b, x2 + (size_t)c * MHALF * 512, nullptr,
        out + (size_t)c * MHALF * 512, nullptr, nullptr);
  }
}

// Round 7
// 1617.573 us; speedup vs baseline: 1.0848x; 1.0781x over previous
//
#include <hip/hip_runtime.h>
#include <hip/hip_bf16.h>
#include <math.h>

// ---------------- problem constants ----------------
#define MROWS 100352      // B*L
#define MHALF 50176
#define DIM   512
#define LL    3136
#define HH    56
#define SSH   3
#define SCALE_QK 0.17677669529663687f

typedef __bf16 bf16;
typedef __bf16 bf16x8 __attribute__((ext_vector_type(8)));
typedef __bf16 bf16x4 __attribute__((ext_vector_type(4)));
typedef float  f32x4  __attribute__((ext_vector_type(4)));

typedef __attribute__((address_space(1))) void* gas_ptr;
typedef __attribute__((address_space(3))) void* las_ptr;

__device__ __forceinline__ void gload_lds16(const void* g, void* l) {
  __builtin_amdgcn_global_load_lds((gas_ptr)g, (las_ptr)l, 16, 0, 0);
}

// window-ordered row r -> natural row index (applies +SS roll, window reverse)
__device__ __forceinline__ int nat_row(int r) {
  int bw = r / 49;
  int n  = r - bw * 49;
  int b  = bw >> 6;
  int wh = (bw >> 3) & 7;
  int ww = bw & 7;
  int i  = n / 7;
  int j  = n - i * 7;
  int hs = wh * 7 + i + SSH; if (hs >= HH) hs -= HH;
  int ws = ww * 7 + j + SSH; if (ws >= HH) ws -= HH;
  return b * LL + hs * HH + ws;
}

// epilogue repack swizzle: byte offset of C[row][col] in the 256x256 bf16 LDS image
__device__ __forceinline__ int swz(int row, int colB) {
  return (row * 512 + colB) ^ (((row >> 2) & 3) << 5);
}

// ---------------- weight transpose + cast: dst[n][k] = (bf16)src[k][n] ----------------
__global__ __launch_bounds__(256) void tcast_kernel(const float* __restrict__ src,
                                                    bf16* __restrict__ dst,
                                                    int Kd, int Nd) {
  __shared__ float t[32][33];
  int tx = threadIdx.x & 31, ty = threadIdx.x >> 5;
  int n0 = blockIdx.x * 32, k0 = blockIdx.y * 32;
  #pragma unroll
  for (int yy = ty; yy < 32; yy += 8)
    t[yy][tx] = src[(size_t)(k0 + yy) * Nd + n0 + tx];
  __syncthreads();
  #pragma unroll
  for (int yy = ty; yy < 32; yy += 8)
    dst[(size_t)(n0 + yy) * Kd + k0 + tx] = (bf16)t[tx][yy];
}

// ---------------- fused rel-pos bias + shift mask table ----------------
// biasM[cls(4)][head(16)][q(49)][k(49)] fp32; cls = (wh==7)<<1 | (ww==7)
__global__ __launch_bounds__(256) void biasM_kernel(const float* __restrict__ table,
                                                    float* __restrict__ biasM) {
  int e = blockIdx.x * 256 + threadIdx.x;
  if (e >= 4 * 16 * 2401) return;
  int k  = e % 49;
  int t  = e / 49;
  int qv = t % 49; t /= 49;
  int head = t & 15;
  int cls  = t >> 4;
  int i1 = qv / 7, j1 = qv - i1 * 7;
  int i2 = k / 7,  j2 = k - i2 * 7;
  float b = table[((i1 - i2 + 6) * 13 + (j1 - j2 + 6)) * 16 + head];
  int labq = ((cls & 2) ? ((i1 < 4) ? 1 : 2) : 0) * 3 + ((cls & 1) ? ((j1 < 4) ? 1 : 2) : 0);
  int labk = ((cls & 2) ? ((i2 < 4) ? 1 : 2) : 0) * 3 + ((cls & 1) ? ((j2 < 4) ? 1 : 2) : 0);
  biasM[e] = b + ((labq == labk) ? 0.f : -100.f);
}

// ---------------- LayerNorm (one wave per row), optional gather / bf16 input ----------------
template<int PERM, int BF16IN>
__global__ __launch_bounds__(256) void ln_kernel(const void* __restrict__ xin,
                                                 const float* __restrict__ gw,
                                                 const float* __restrict__ bw_,
                                                 bf16* __restrict__ out) {
  int wave = threadIdx.x >> 6, lane = threadIdx.x & 63;
  int r = blockIdx.x * 4 + wave;
  int src = PERM ? nat_row(r) : r;
  float f[8];
  if (BF16IN) {
    bf16x8 vv = *(const bf16x8*)((const bf16*)xin + (size_t)src * DIM + lane * 8);
    #pragma unroll
    for (int j = 0; j < 8; j++) f[j] = (float)vv[j];
  } else {
    const float* px = (const float*)xin + (size_t)src * DIM + lane * 8;
    float4 v0 = *(const float4*)px;
    float4 v1 = *(const float4*)(px + 4);
    f[0]=v0.x; f[1]=v0.y; f[2]=v0.z; f[3]=v0.w; f[4]=v1.x; f[5]=v1.y; f[6]=v1.z; f[7]=v1.w;
  }
  float s = 0.f, q = 0.f;
  #pragma unroll
  for (int j = 0; j < 8; j++) { s += f[j]; q += f[j] * f[j]; }
  #pragma unroll
  for (int m = 1; m < 64; m <<= 1) { s += __shfl_xor(s, m); q += __shfl_xor(q, m); }
  float mean = s * (1.f / DIM);
  float var  = q * (1.f / DIM) - mean * mean;
  float rstd = rsqrtf(var + 1e-5f);
  int c0 = lane * 8;
  float4 g0 = *(const float4*)(gw + c0),  g1 = *(const float4*)(gw + c0 + 4);
  float4 b0 = *(const float4*)(bw_ + c0), b1 = *(const float4*)(bw_ + c0 + 4);
  float gg[8] = {g0.x,g0.y,g0.z,g0.w,g1.x,g1.y,g1.z,g1.w};
  float bb[8] = {b0.x,b0.y,b0.z,b0.w,b1.x,b1.y,b1.z,b1.w};
  bf16x8 o;
  #pragma unroll
  for (int j = 0; j < 8; j++) o[j] = (bf16)((f[j] - mean) * rstd * gg[j] + bb[j]);
  *(bf16x8*)(out + (size_t)r * DIM + c0) = o;
}

// ================= 256x256 8-phase GEMM (T1+T2+T3+T4+T5) =================
// MODE 1: x2b[nat(row)] = bf16(residF[nat(row)] + acc + bias)      (proj, bf16 out)
// MODE 2: outB = bf16(gelu_exact(acc + bias))                      (fc1)
// MODE 3: outF[row] = float(residB[row]) + acc + bias      (fp32)  (fc2)
// MODE 4: qkv split head-major: Q/K/V -> [wid][nn][32]
// All modes: coalesced epilogue via 128KB LDS repack (swz).

#define MF(a,b,c) __builtin_amdgcn_mfma_f32_16x16x32_bf16((a),(b),(c),0,0,0)
#define BAR() __builtin_amdgcn_s_barrier()
#define WLG() asm volatile("s_waitcnt lgkmcnt(0)" ::: "memory")
#define WVM(n) asm volatile("s_waitcnt vmcnt(" #n ")" ::: "memory")

template<int MODE, int KD, int ND>
__global__ __launch_bounds__(512, 2) void gemm256_kernel(const bf16* __restrict__ A,
                                                         const bf16* __restrict__ Bt,
                                                         const float* __restrict__ bias,
                                                         const float* __restrict__ residF,
                                                         const bf16* __restrict__ residB,
                                                         bf16* __restrict__ outB,
                                                         float* __restrict__ outF,
                                                         bf16* __restrict__ outK,
                                                         bf16* __restrict__ outV) {
  constexpr int NTN = ND / 256;
  constexpr int NI  = KD / 128;      // iterations; 2 K-tiles (of 64) each
  __shared__ bf16 lds[65536];        // 128 KiB

  const int tid = threadIdx.x, lane = tid & 63, wv = tid >> 6;
  const int lr = lane & 15, lg = lane >> 4;
  const int wm = wv >> 2, wn = wv & 3;     // 2 x 4 wave grid

  // bijective XCD swizzle (m204)
  int nwg = gridDim.x, orig = blockIdx.x;
  int q = nwg >> 3, r = nwg & 7, xcd = orig & 7;
  int wgid = (xcd < r ? xcd * (q + 1) : r * (q + 1) + (xcd - r) * q) + (orig >> 3);
  int tm = wgid / NTN, tn = wgid % NTN;

  const bf16* gA = A  + (size_t)tm * 256 * KD;
  const bf16* gB = Bt + (size_t)tn * 256 * KD;

  // ds_read bases (elems), swizzled (st_16x32)
  const int klg  = (lg * 8) ^ ((lr & 8) ? 16 : 0);
  const int a_rd = (wm * 128 + lr) * 32 + klg;
  const int b_rd = (wn * 64 + lr) * 32 + klg;

  // staging constants
  const int kbOffE = (wv >> 2) * 8192;
  const int kGlob  = (wv >> 2) * 32 + (((lane & 3) * 8) ^ ((lane & 32) ? 16 : 0));
  const int rl0    = ((wv * 2) & 7) * 16 + (lane >> 2);
  const int rl1    = rl0 + 16;
  const int c0off  = ((wv * 2) & 7) * 512;

#define STG(GP, DB, h, koff) \
  gload_lds16((GP) + (size_t)((h) * 128 + rl0) * KD + (koff) + kGlob, \
              (void*)(lds + (DB) + kbOffE + (h) * 4096 + c0off)); \
  gload_lds16((GP) + (size_t)((h) * 128 + rl1) * KD + (koff) + kGlob, \
              (void*)(lds + (DB) + kbOffE + (h) * 4096 + c0off + 512));

  f32x4 acc[8][4];
  #pragma unroll
  for (int i = 0; i < 8; i++)
    #pragma unroll
    for (int j = 0; j < 4; j++) { acc[i][j][0]=0.f; acc[i][j][1]=0.f; acc[i][j][2]=0.f; acc[i][j][3]=0.f; }

  bf16x8 Af[4][2], Bf0[2][2], Bf1[2][2];

  // prologue: tile0 -> b0, tile1 -> b1
  STG(gA, 0,     0, 0)  STG(gA, 0,     1, 0)
  STG(gB, 16384, 0, 0)  STG(gB, 16384, 1, 0)
  STG(gA, 32768, 0, 64) STG(gA, 32768, 1, 64)
  STG(gB, 49152, 0, 64) STG(gB, 49152, 1, 64)
  WVM(8); BAR();

#define PHASES(AB, BB, DOST, KST, ENDW) { \
    _Pragma("unroll") for (int m = 0; m < 4; m++) { \
      Af[m][0] = *(const bf16x8*)(lds + (AB) + m * 512 + a_rd); \
      Af[m][1] = *(const bf16x8*)(lds + (AB) + 8192 + m * 512 + a_rd); } \
    _Pragma("unroll") for (int n = 0; n < 2; n++) { \
      Bf0[n][0] = *(const bf16x8*)(lds + (BB) + n * 512 + b_rd); \
      Bf0[n][1] = *(const bf16x8*)(lds + (BB) + 8192 + n * 512 + b_rd); } \
    BAR(); WLG(); __builtin_amdgcn_s_setprio(1); \
    _Pragma("unroll") for (int m = 0; m < 4; m++) \
      _Pragma("unroll") for (int n = 0; n < 2; n++) { \
        acc[m][n] = MF(Af[m][0], Bf0[n][0], acc[m][n]); \
        acc[m][n] = MF(Af[m][1], Bf0[n][1], acc[m][n]); } \
    __builtin_amdgcn_s_setprio(0); BAR(); \
    _Pragma("unroll") for (int n = 0; n < 2; n++) { \
      Bf1[n][0] = *(const bf16x8*)(lds + (BB) + (n + 2) * 512 + b_rd); \
      Bf1[n][1] = *(const bf16x8*)(lds + (BB) + 8192 + (n + 2) * 512 + b_rd); } \
    if (DOST) { STG(gB, (BB), 0, (KST)) } \
    BAR(); WLG(); __builtin_amdgcn_s_setprio(1); \
    _Pragma("unroll") for (int m = 0; m < 4; m++) \
      _Pragma("unroll") for (int n = 0; n < 2; n++) { \
        acc[m][n + 2] = MF(Af[m][0], Bf1[n][0], acc[m][n + 2]); \
        acc[m][n + 2] = MF(Af[m][1], Bf1[n][1], acc[m][n + 2]); } \
    __builtin_amdgcn_s_setprio(0); BAR(); \
    _Pragma("unroll") for (int m = 0; m < 4; m++) { \
      Af[m][0] = *(const bf16x8*)(lds + (AB) + (m + 4) * 512 + a_rd); \
      Af[m][1] = *(const bf16x8*)(lds + (AB) + 8192 + (m + 4) * 512 + a_rd); } \
    if (DOST) { STG(gB, (BB), 1, (KST)) STG(gA, (AB), 0, (KST)) } \
    BAR(); WLG(); __builtin_amdgcn_s_setprio(1); \
    _Pragma("unroll") for (int m = 0; m < 4; m++) \
      _Pragma("unroll") for (int n = 0; n < 2; n++) { \
        acc[m + 4][n + 2] = MF(Af[m][0], Bf1[n][0], acc[m + 4][n + 2]); \
        acc[m + 4][n + 2] = MF(Af[m][1], Bf1[n][1], acc[m + 4][n + 2]); } \
    __builtin_amdgcn_s_setprio(0); BAR(); \
    if (DOST) { STG(gA, (AB), 1, (KST)) } \
    BAR(); WLG(); __builtin_amdgcn_s_setprio(1); \
    _Pragma("unroll") for (int m = 0; m < 4; m++) \
      _Pragma("unroll") for (int n = 0; n < 2; n++) { \
        acc[m + 4][n] = MF(Af[m][0], Bf0[n][0], acc[m + 4][n]); \
        acc[m + 4][n] = MF(Af[m][1], Bf0[n][1], acc[m + 4][n]); } \
    __builtin_amdgcn_s_setprio(0); ENDW; BAR(); \
  }

  #pragma unroll 1
  for (int I = 0; I < NI - 1; ++I) {
    int ke = (2 * I + 2) * 64;
    PHASES(0,     16384, 1, ke,      WVM(6));
    PHASES(32768, 49152, 1, ke + 64, WVM(6));
  }
  PHASES(0,     16384, 0, 0, WVM(0));
  PHASES(32768, 49152, 0, 0, ((void)0));

#undef PHASES
#undef STG

  // ---------------- repack epilogue (coalesced) ----------------
  char* ldsb = (char*)lds;
  float bias4[4];
  #pragma unroll
  for (int fn = 0; fn < 4; fn++) bias4[fn] = bias[tn * 256 + wn * 64 + fn * 16 + lr];
  __syncthreads();
  #pragma unroll
  for (int fm = 0; fm < 8; fm++)
    #pragma unroll
    for (int fn = 0; fn < 4; fn++)
      #pragma unroll
      for (int rr = 0; rr < 4; rr++) {
        int row = wm * 128 + fm * 16 + lg * 4 + rr;
        int colB = (wn * 64 + fn * 16 + lr) * 2;
        float v = acc[fm][fn][rr] + bias4[fn];
        if (MODE == 2) v = 0.5f * v * (1.f + erff(v * 0.70710678118654752f));
        *(bf16*)(ldsb + swz(row, colB)) = (bf16)v;
      }
  __syncthreads();

  const int lrow = tid >> 5, cu = tid & 31;
  bf16* dst4 = nullptr;
  if (MODE == 4) {
    int third = (tn * 256) >> 9;
    dst4 = third == 0 ? outB : (third == 1 ? outK : outV);
  }
  #pragma unroll 4
  for (int s = 0; s < 16; s++) {
    int row = s * 16 + lrow;
    bf16x8 v = *(const bf16x8*)(ldsb + swz(row, cu * 16));
    int grow = tm * 256 + row;
    int gcol = tn * 256 + cu * 8;
    if (MODE == 2) {
      *(bf16x8*)(outB + (size_t)grow * ND + gcol) = v;
    } else if (MODE == 1) {
      int orow = nat_row(grow);
      const float* rp = residF + (size_t)orow * 512 + gcol;
      float4 r0 = *(const float4*)rp, r1 = *(const float4*)(rp + 4);
      bf16x8 o;
      o[0] = (bf16)(r0.x + (float)v[0]); o[1] = (bf16)(r0.y + (float)v[1]);
      o[2] = (bf16)(r0.z + (float)v[2]); o[3] = (bf16)(r0.w + (float)v[3]);
      o[4] = (bf16)(r1.x + (float)v[4]); o[5] = (bf16)(r1.y + (float)v[5]);
      o[6] = (bf16)(r1.z + (float)v[6]); o[7] = (bf16)(r1.w + (float)v[7]);
      *(bf16x8*)(outB + (size_t)orow * 512 + gcol) = o;
    } else if (MODE == 3) {
      bf16x8 rb = *(const bf16x8*)(residB + (size_t)grow * 512 + gcol);
      float4 o0, o1;
      o0.x = (float)rb[0] + (float)v[0]; o0.y = (float)rb[1] + (float)v[1];
      o0.z = (float)rb[2] + (float)v[2]; o0.w = (float)rb[3] + (float)v[3];
      o1.x = (float)rb[4] + (float)v[4]; o1.y = (float)rb[5] + (float)v[5];
      o1.z = (float)rb[6] + (float)v[6]; o1.w = (float)rb[7] + (float)v[7];
      float* op = outF + (size_t)grow * 512 + gcol;
      *(float4*)op = o0; *(float4*)(op + 4) = o1;
    } else { // MODE 4
      int win = grow / 49, nn = grow - win * 49;
      int head = (gcol >> 5) & 15, d = gcol & 31;
      *(bf16x8*)(dst4 + (size_t)(win * 16 + head) * 1568 + nn * 32 + d) = v;
    }
  }
}

// ---------------- windowed attention: one wave per (window, head) ----------------
// Q/K/V head-major [wid][nn][32]; V transposed through per-wave LDS.
__global__ __launch_bounds__(256) void attn_kernel(const bf16* __restrict__ Qb,
                                                   const bf16* __restrict__ Kb,
                                                   const bf16* __restrict__ Vb,
                                                   const float* __restrict__ biasM,
                                                   bf16* __restrict__ attnO) {
  __shared__ bf16 P[4][64 * 72];    // per-wave P tile, row stride 72 elems
  __shared__ bf16 Vs[4][49 * 36];   // per-wave V tile, row stride 36 elems (72 B)
  int wave = threadIdx.x >> 6, lane = threadIdx.x & 63;
  int lr = lane & 15, lg = lane >> 4;
  int wid = blockIdx.x * 4 + wave;      // win*16 + head
  int win = wid >> 4, head = wid & 15;
  int wh = (win >> 3) & 7, ww = win & 7;
  int cls = ((wh == 7) ? 2 : 0) | ((ww == 7) ? 1 : 0);
  const bf16* qp = Qb + (size_t)wid * 1568;
  const bf16* kp = Kb + (size_t)wid * 1568;
  const bf16* vp = Vb + (size_t)wid * 1568;
  const float* bp = biasM + (size_t)cls * 38416 + head * 2401;

  // stage V [49][32] -> Vs rows stride 36 (coalesced 16B global loads)
  for (int i = lane; i < 196; i += 64) {
    bf16x8 v = *(const bf16x8*)(vp + i * 8);
    int nn = i >> 2, d = (i & 3) * 8;
    ((bf16x4*)(&Vs[wave][nn * 36 + d]))[0] = ((bf16x4*)&v)[0];
    ((bf16x4*)(&Vs[wave][nn * 36 + d + 4]))[0] = ((bf16x4*)&v)[1];
  }

  f32x4 zero4 = {0.f, 0.f, 0.f, 0.f};
  bf16x8 aq[4], bk[4];
  #pragma unroll
  for (int mi = 0; mi < 4; mi++) {
    int qq = mi * 16 + lr; if (qq > 48) qq = 48;
    aq[mi] = *(const bf16x8*)(qp + qq * 32 + lg * 8);
    bk[mi] = *(const bf16x8*)(kp + qq * 32 + lg * 8);
  }
  f32x4 sacc[4][4];
  #pragma unroll
  for (int mi = 0; mi < 4; mi++)
    #pragma unroll
    for (int ni = 0; ni < 4; ni++)
      sacc[mi][ni] = __builtin_amdgcn_mfma_f32_16x16x32_bf16(aq[mi], bk[ni], zero4, 0, 0, 0);

  float rsum[4][4];
  #pragma unroll
  for (int mi = 0; mi < 4; mi++) {
    #pragma unroll
    for (int rr = 0; rr < 4; rr++) {
      int qrow = mi * 16 + lg * 4 + rr;
      int qc = qrow > 48 ? 48 : qrow;
      const float* bq = bp + qc * 49;
      float pv[4];
      float mv = -3.0e30f;
      #pragma unroll
      for (int ni = 0; ni < 4; ni++) {
        int key = ni * 16 + lr;
        float v = (key < 49) ? sacc[mi][ni][rr] * SCALE_QK + bq[key] : -1e30f;
        pv[ni] = v;
        mv = fmaxf(mv, v);
      }
      #pragma unroll
      for (int m = 1; m < 16; m <<= 1) mv = fmaxf(mv, __shfl_xor(mv, m));
      float sum = 0.f;
      #pragma unroll
      for (int ni = 0; ni < 4; ni++) {
        float p = __expf(pv[ni] - mv);
        sum += p;
        P[wave][qrow * 72 + ni * 16 + lr] = (bf16)p;
      }
      #pragma unroll
      for (int m = 1; m < 16; m <<= 1) sum += __shfl_xor(sum, m);
      rsum[mi][rr] = sum;
    }
  }
  __syncthreads();

  f32x4 oacc[4][2];
  #pragma unroll
  for (int mi = 0; mi < 4; mi++) { oacc[mi][0] = zero4; oacc[mi][1] = zero4; }
  #pragma unroll
  for (int ks = 0; ks < 2; ks++) {
    bf16x8 bv[2];
    #pragma unroll
    for (int n2 = 0; n2 < 2; n2++)
      #pragma unroll
      for (int j = 0; j < 8; j++) {
        int kv = ks * 32 + lg * 8 + j;
        if (kv > 48) kv = 48;           // P there is exactly 0
        bv[n2][j] = Vs[wave][kv * 36 + n2 * 16 + lr];
      }
    #pragma unroll
    for (int mi = 0; mi < 4; mi++) {
      bf16x8 ap = *(const bf16x8*)(&P[wave][(mi * 16 + lr) * 72 + ks * 32 + lg * 8]);
      #pragma unroll
      for (int n2 = 0; n2 < 2; n2++)
        oacc[mi][n2] = __builtin_amdgcn_mfma_f32_16x16x32_bf16(ap, bv[n2], oacc[mi][n2], 0, 0, 0);
    }
  }
  #pragma unroll
  for (int mi = 0; mi < 4; mi++) {
    #pragma unroll
    for (int rr = 0; rr < 4; rr++) {
      int qrow = mi * 16 + lg * 4 + rr;
      if (qrow < 49) {
        float inv = 1.f / rsum[mi][rr];
        #pragma unroll
        for (int n2 = 0; n2 < 2; n2++)
          attnO[((size_t)win * 49 + qrow) * DIM + head * 32 + n2 * 16 + lr] =
              (bf16)(oacc[mi][n2][rr] * inv);
      }
    }
  }
}

// ---------------- launch ----------------
extern "C" void kernel_launch(void* const* d_in, const int* in_sizes, int n_in,
                              void* d_out, int out_size, void* d_ws, size_t ws_size,
                              hipStream_t stream) {
  const float* x      = (const float*)d_in[0];
  const float* n1g    = (const float*)d_in[1];
  const float* n1b    = (const float*)d_in[2];
  const float* qkv_w  = (const float*)d_in[3];
  const float* qkv_b  = (const float*)d_in[4];
  const float* tabl   = (const float*)d_in[5];
  const float* proj_w = (const float*)d_in[6];
  const float* proj_b = (const float*)d_in[7];
  const float* n2g    = (const float*)d_in[8];
  const float* n2b    = (const float*)d_in[9];
  const float* fc1_w  = (const float*)d_in[10];
  const float* fc1_b  = (const float*)d_in[11];
  const float* fc2_w  = (const float*)d_in[12];
  const float* fc2_b  = (const float*)d_in[13];
  float* out = (float*)d_out;

  char* ws = (char*)d_ws;
  // region 0: RegA (X1n -> attnO -> X2n)                 102,760,448 B
  // region 1: Qb + Kb (later h1 chunks = RegB)           205,520,896 B
  // region 2: Vb | later x2b (bf16) ; biasM after        102,760,448 B + 615 KB
  // region 3: bf16 weights                                 6,291,456 B
  bf16*  RegA   = (bf16*)ws;
  bf16*  Qb     = (bf16*)(ws + 102760448);
  bf16*  Kb     = (bf16*)(ws + 102760448 + 102760448);
  bf16*  RegB   = Qb;  // h1 chunks reuse Qb/Kb space
  char*  reg2   = ws + 308281344;
  bf16*  Vb     = (bf16*)reg2;
  bf16*  x2b    = (bf16*)reg2;                 // aliases Vb (dead after attn)
  float* biasM  = (float*)(reg2 + 102760448);
  bf16*  qkvWt  = (bf16*)(ws + 308281344 + 205520896);
  bf16*  projWt = qkvWt + 1536 * 512;
  bf16*  fc1Wt  = projWt + 512 * 512;
  bf16*  fc2Wt  = fc1Wt + 2048 * 512;

  // bias+mask table (615 KB) and weights -> bf16 (N,K)
  biasM_kernel<<<(4 * 16 * 2401 + 255) / 256, 256, 0, stream>>>(tabl, biasM);
  tcast_kernel<<<dim3(1536 / 32, 512 / 32), 256, 0, stream>>>(qkv_w, qkvWt, 512, 1536);
  tcast_kernel<<<dim3(512 / 32, 512 / 32), 256, 0, stream>>>(proj_w, projWt, 512, 512);
  tcast_kernel<<<dim3(2048 / 32, 512 / 32), 256, 0, stream>>>(fc1_w, fc1Wt, 512, 2048);
  tcast_kernel<<<dim3(512 / 32, 2048 / 32), 256, 0, stream>>>(fc2_w, fc2Wt, 2048, 512);

  // LN1 + shift + window partition (window-ordered bf16 rows)
  ln_kernel<1, 0><<<MROWS / 4, 256, 0, stream>>>((const void*)x, n1g, n1b, RegA);
  // qkv GEMM, head-major split epilogue
  gemm256_kernel<4, 512, 1536><<<(MROWS / 256) * 6, 512, 0, stream>>>(
      RegA, qkvWt, qkv_b, nullptr, nullptr, Qb, nullptr, Kb, Vb);
  // attention (2048 windows * 16 heads, 4 waves/block)
  attn_kernel<<<2048 * 16 / 4, 256, 0, stream>>>(Qb, Kb, Vb, biasM, RegA);
  // proj + residual + window-reverse scatter -> x2b (bf16, natural order)
  gemm256_kernel<1, 512, 512><<<(MROWS / 256) * 2, 512, 0, stream>>>(
      RegA, projWt, proj_b, x, nullptr, x2b, nullptr, nullptr, nullptr);
  // LN2 (bf16 input)
  ln_kernel<0, 1><<<MROWS / 4, 256, 0, stream>>>((const void*)x2b, n2g, n2b, RegA);
  // MLP in two row-chunks (h1 chunk reuses RegB = Qb/Kb space)
  for (int c = 0; c < 2; ++c) {
    const bf16* a1 = RegA + (size_t)c * MHALF * 512;
    gemm256_kernel<2, 512, 2048><<<(MHALF / 256) * 8, 512, 0, stream>>>(
        a1, fc1Wt, fc1_b, nullptr, nullptr, RegB, nullptr, nullptr, nullptr);
    gemm256_kernel<3, 2048, 512><<<(MHALF / 256) * 2, 512, 0, stream>>>(
        RegB, fc2Wt, fc2_b, nullptr, x2b + (size_t)c * MHALF * 512, nullptr,
        out + (size_t)c * MHALF * 512, nullptr, nullptr);
  }
}